// Round 2
// baseline (1099.295 us; speedup 1.0000x reference)
//
#include <hip/hip_runtime.h>
#include <math.h>

#define B_SZ   8192
#define FEATN  1024
#define DCOL   4096
#define NS     5
#define NN     7      // nodes
#define HIDN   64
#define NTREE  448    // 7*64
#define NDIR   256
#define NTOT   704

// ---------------- GEMM: hidden[b][n] = sum_k features[b][k] * W[n][k] ----------------
// W = concat(tw1 flat (448x1024), dw1 (256x1024)); bias added later in gates kernel.
// R1 resubmit: R0 bench died in the broker (container failed twice) with no
// test output; kernel audited for OOB/misalignment/graph-capture hazards.
#define BM 128
#define BN 64
#define BK 16
#define LDA 132   // pad: 132%32=4 -> no bank conflict on transposed scatter; 132*4 % 16 == 0
#define LDB 68

__global__ __launch_bounds__(256) void htg_gemm(
    const float* __restrict__ A, const float* __restrict__ tw1,
    const float* __restrict__ dw1, float* __restrict__ hidden)
{
    __shared__ float As[BK * LDA];
    __shared__ float Bs[BK * LDB];
    const int tid = threadIdx.x;
    const int bm0 = blockIdx.x * BM;
    const int bn0 = blockIdx.y * BN;
    // whole 64-wide N tile is either tree weights or direct weights (448 = 7*64)
    const float* Wsrc = (bn0 < NTREE) ? (tw1 + (size_t)bn0 * FEATN)
                                      : (dw1 + (size_t)(bn0 - NTREE) * FEATN);
    const int ty  = tid >> 4;   // 0..15 -> rows ty*8..+7
    const int tx  = tid & 15;   // 0..15 -> cols tx*4..+3
    const int lr  = tid >> 2;   // 0..63 load row
    const int lc4 = tid & 3;    // 0..3  load col (float4 granularity)

    float acc[8][4];
#pragma unroll
    for (int i = 0; i < 8; ++i)
#pragma unroll
        for (int j = 0; j < 4; ++j) acc[i][j] = 0.f;

    float4 aR0, aR1, bR;
    {
        const float* Ap = A + (size_t)(bm0 + lr) * FEATN + lc4 * 4;
        aR0 = *(const float4*)(Ap);
        aR1 = *(const float4*)(Ap + (size_t)64 * FEATN);
        bR  = *(const float4*)(Wsrc + (size_t)lr * FEATN + lc4 * 4);
    }
    const int KT = FEATN / BK;
    for (int kt = 0; kt < KT; ++kt) {
        {   // scatter regs -> LDS transposed [k][m]
            float av0[4] = {aR0.x, aR0.y, aR0.z, aR0.w};
            float av1[4] = {aR1.x, aR1.y, aR1.z, aR1.w};
            float bv[4]  = {bR.x,  bR.y,  bR.z,  bR.w};
#pragma unroll
            for (int j = 0; j < 4; ++j) {
                As[(lc4 * 4 + j) * LDA + lr]      = av0[j];
                As[(lc4 * 4 + j) * LDA + lr + 64] = av1[j];
                Bs[(lc4 * 4 + j) * LDB + lr]      = bv[j];
            }
        }
        __syncthreads();
        if (kt + 1 < KT) {  // prefetch next tile into regs (hide under compute)
            const int k0 = (kt + 1) * BK;
            const float* Ap = A + (size_t)(bm0 + lr) * FEATN + k0 + lc4 * 4;
            aR0 = *(const float4*)(Ap);
            aR1 = *(const float4*)(Ap + (size_t)64 * FEATN);
            bR  = *(const float4*)(Wsrc + (size_t)lr * FEATN + k0 + lc4 * 4);
        }
#pragma unroll
        for (int kk = 0; kk < BK; ++kk) {
            float4 a0 = *(const float4*)&As[kk * LDA + ty * 8];
            float4 a1 = *(const float4*)&As[kk * LDA + ty * 8 + 4];
            float4 b  = *(const float4*)&Bs[kk * LDB + tx * 4];
            float av[8] = {a0.x, a0.y, a0.z, a0.w, a1.x, a1.y, a1.z, a1.w};
            float bv[4] = {b.x, b.y, b.z, b.w};
#pragma unroll
            for (int i = 0; i < 8; ++i)
#pragma unroll
                for (int j = 0; j < 4; ++j)
                    acc[i][j] = fmaf(av[i], bv[j], acc[i][j]);
        }
        __syncthreads();
    }
#pragma unroll
    for (int i = 0; i < 8; ++i) {
        const int row = bm0 + ty * 8 + i;
        float4 v = make_float4(acc[i][0], acc[i][1], acc[i][2], acc[i][3]);
        *(float4*)&hidden[(size_t)row * NTOT + bn0 + tx * 4] = v;
    }
}

// ---------------- gates kernel: one wave (64 threads) per batch row ----------------
__device__ inline float wredsum(float v) {
#pragma unroll
    for (int o = 32; o > 0; o >>= 1) v += __shfl_xor(v, o, 64);
    return v;
}
__device__ inline float gelu_exact(float x) {
    return 0.5f * x * (1.f + erff(x * 0.70710678118654752f));
}
__device__ inline void softmax5(float* v) {
    float m = v[0];
#pragma unroll
    for (int s = 1; s < NS; ++s) m = fmaxf(m, v[s]);
    float sum = 0.f;
#pragma unroll
    for (int s = 0; s < NS; ++s) { v[s] = expf(v[s] - m); sum += v[s]; }
    float inv = 1.f / sum;
#pragma unroll
    for (int s = 0; s < NS; ++s) v[s] *= inv;
}

__global__ __launch_bounds__(64) void htg_gates(
    const float* __restrict__ hidden,
    const float* __restrict__ tb1, const float* __restrict__ tg,
    const float* __restrict__ tbn, const float* __restrict__ tw2,
    const float* __restrict__ tb2,
    const float* __restrict__ lw1, const float* __restrict__ lb1,
    const float* __restrict__ lw2, const float* __restrict__ lb2,
    const float* __restrict__ db1, const float* __restrict__ dw2,
    const float* __restrict__ db2, const float* __restrict__ cw,
    float* __restrict__ gates_out)
{
    const int b = blockIdx.x;
    const int l = threadIdx.x;
    const float* hb = hidden + (size_t)b * NTOT;

    float np0[NN], np1[NN];
#pragma unroll
    for (int n = 0; n < NN; ++n) {
        float x  = hb[n * 64 + l] + tb1[n * 64 + l];
        float s  = wredsum(x);
        float sq = wredsum(x * x);
        float mu  = s * (1.f / 64.f);
        float var = sq * (1.f / 64.f) - mu * mu;
        float xn  = (x - mu) * rsqrtf(var + 1e-5f);
        xn = xn * tg[n * 64 + l] + tbn[n * 64 + l];
        float g = gelu_exact(xn);
        float o0 = wredsum(g * tw2[(n * 2 + 0) * 64 + l]) + tb2[n * 2 + 0];
        float o1 = wredsum(g * tw2[(n * 2 + 1) * 64 + l]) + tb2[n * 2 + 1];
        // softmax([o0,o1]/0.5): p0 = 1/(1+exp(2*(o1-o0)))
        float p0 = 1.f / (1.f + expf(2.f * (o1 - o0)));
        np0[n] = p0; np1[n] = 1.f - p0;
    }
    // leaf probs (redundant per lane — all lanes hold reduced values)
    float lp[8];
#pragma unroll
    for (int leaf = 0; leaf < 8; ++leaf) {
        const int c0 = (leaf >> 2) & 1, c1 = (leaf >> 1) & 1, c2 = leaf & 1;
        float v0 = c0 ? np1[0] : np0[0];
        float v1 = c1 ? np1[1 + c0] : np0[1 + c0];
        float v2 = c2 ? np1[3 + 2 * c0 + c1] : np0[3 + 2 * c0 + c1];
        lp[leaf] = v0 * v1 * v2;
    }
    float t[10];
#pragma unroll
    for (int j = 0; j < 10; ++j) {
        float a = lb1[j];
#pragma unroll
        for (int leaf = 0; leaf < 8; ++leaf) a = fmaf(lp[leaf], lw1[j * 8 + leaf], a);
        t[j] = gelu_exact(a);
    }
    float tgt[NS];
#pragma unroll
    for (int s = 0; s < NS; ++s) {
        float a = lb2[s];
#pragma unroll
        for (int j = 0; j < 10; ++j) a = fmaf(t[j], lw2[s * 10 + j], a);
        tgt[s] = a;
    }
    softmax5(tgt);

    // direct path
    float dacc[NS] = {0.f, 0.f, 0.f, 0.f, 0.f};
#pragma unroll
    for (int i = 0; i < 4; ++i) {
        const int j = i * 64 + l;
        float d = gelu_exact(hb[NTREE + j] + db1[j]);
#pragma unroll
        for (int s = 0; s < NS; ++s) dacc[s] = fmaf(d, dw2[s * 256 + j], dacc[s]);
    }
    float dgt[NS];
#pragma unroll
    for (int s = 0; s < NS; ++s) dgt[s] = wredsum(dacc[s]) + db2[s];
    softmax5(dgt);

    const float w = 1.f / (1.f + expf(-cw[0]));
    float g5[NS]; float sum = 0.f;
#pragma unroll
    for (int s = 0; s < NS; ++s) { g5[s] = w * tgt[s] + (1.f - w) * dgt[s]; sum += g5[s]; }
    float inv = 1.f / sum;
    if (l < NS) gates_out[(size_t)b * NS + l] = g5[l] * inv;
}

// ---------------- combine: out[b][d] = sum_s gates[b][s] * logits[s][b][d] ----------------
__global__ __launch_bounds__(256) void htg_combine(
    const float* __restrict__ logits, const float* __restrict__ gates,
    float* __restrict__ out)
{
    const int b  = blockIdx.x >> 2;                        // 4 blocks per row
    const int d4 = ((blockIdx.x & 3) << 8) + threadIdx.x;  // float4 index in row
    float g[NS];
#pragma unroll
    for (int s = 0; s < NS; ++s) g[s] = gates[(size_t)b * NS + s];  // block-uniform -> scalar loads
    const float4* lp = (const float4*)logits;
    const size_t base = (size_t)b * (DCOL / 4) + d4;
    float4 a = make_float4(0.f, 0.f, 0.f, 0.f);
#pragma unroll
    for (int s = 0; s < NS; ++s) {
        float4 v = lp[(size_t)s * B_SZ * (DCOL / 4) + base];
        a.x = fmaf(g[s], v.x, a.x);
        a.y = fmaf(g[s], v.y, a.y);
        a.z = fmaf(g[s], v.z, a.z);
        a.w = fmaf(g[s], v.w, a.w);
    }
    ((float4*)out)[base] = a;
}

extern "C" void kernel_launch(void* const* d_in, const int* in_sizes, int n_in,
                              void* d_out, int out_size, void* d_ws, size_t ws_size,
                              hipStream_t stream) {
    const float* features = (const float*)d_in[0];
    const float* logits   = (const float*)d_in[1];
    const float* tw1      = (const float*)d_in[2];
    const float* tb1      = (const float*)d_in[3];
    const float* tg       = (const float*)d_in[4];
    const float* tbn      = (const float*)d_in[5];
    const float* tw2      = (const float*)d_in[6];
    const float* tb2      = (const float*)d_in[7];
    const float* lw1      = (const float*)d_in[8];
    const float* lb1      = (const float*)d_in[9];
    const float* lw2      = (const float*)d_in[10];
    const float* lb2      = (const float*)d_in[11];
    const float* dw1      = (const float*)d_in[12];
    const float* db1      = (const float*)d_in[13];
    const float* dw2      = (const float*)d_in[14];
    const float* db2      = (const float*)d_in[15];
    const float* cw       = (const float*)d_in[16];

    float* out = (float*)d_out;
    float* gates = out + (size_t)B_SZ * DCOL;  // tail of d_out (output 1)

    const size_t hidden_bytes = (size_t)B_SZ * NTOT * sizeof(float);
    // hidden scratch: prefer d_ws; fall back to front of d_out (combine overwrites it last)
    float* hidden = (ws_size >= hidden_bytes) ? (float*)d_ws : (float*)d_out;

    dim3 gemm_grid(B_SZ / BM, NTOT / BN);  // 64 x 11
    htg_gemm<<<gemm_grid, 256, 0, stream>>>(features, tw1, dw1, hidden);

    htg_gates<<<B_SZ, 64, 0, stream>>>(hidden, tb1, tg, tbn, tw2, tb2,
                                       lw1, lb1, lw2, lb2, db1, dw2, db2, cw,
                                       gates);

    htg_combine<<<B_SZ * 4, 256, 0, stream>>>(logits, gates, out);
}